// Round 8
// baseline (74.927 us; speedup 1.0000x reference)
//
#include <hip/hip_runtime.h>

// Problem constants (match the reference's module-level B, C, H, W, L)
#define B_  8
#define C_  32
#define HW_ (512 * 512)
#define L_  512

#define CG            8                      // channels per block, TWO batches of 4
#define GROUPS        (C_ / CG)              // 4 -> maps re-read 4x (was 8x)
#define PIX_PER_BLOCK 4096
#define THREADS       256
#define BLOCKS_PER_B  (HW_ / PIX_PER_BLOCK)  // 64

// Fixed-point scale: input ~N(0,1), bin sums |.| <~ 150 -> 150*2^20 = 1.6e8 << 2^31.
// Quantization: <=0.5 ulp = 2^-21 per term, <=1024 terms/bin -> <=5e-4 abs error.
#define SCALE_F     1048576.0f               // 2^20
#define INV_SCALE_F (1.0f / 1048576.0f)

typedef float f32x4 __attribute__((ext_vector_type(4)));
typedef int   i32x4 __attribute__((ext_vector_type(4)));

// LDS int histogram + native ds_add_u32 (no-return). 16 KiB LDS; 8 blocks/CU
// (thread-limited), 32 waves/CU. Channel loads in two batches of 4 so peak
// live float4 count stays at 4 (r5's monolithic CG=8 hoisted 8 -> VGPR blowup).
__global__ __launch_bounds__(THREADS, 8)
void pool_accum(const float* __restrict__ input,      // [B,C,H,W]
                const int*   __restrict__ indmap,     // [B,H,W]
                const int*   __restrict__ out_count,  // [B,L]
                const int*   __restrict__ valid,      // [B,H,W]
                float*       __restrict__ out)        // [B,C,L] (pre-zeroed)
{
    __shared__ unsigned acc[CG * L_];   // 16 KiB

    const int bid   = blockIdx.x;
    const int b     = bid / (GROUPS * BLOCKS_PER_B);
    const int rem   = bid % (GROUPS * BLOCKS_PER_B);
    const int g     = rem / BLOCKS_PER_B;     // channel group
    const int chunk = rem % BLOCKS_PER_B;     // pixel chunk
    const int t     = threadIdx.x;

    for (int i = t; i < CG * L_; i += THREADS) acc[i] = 0u;
    __syncthreads();

    const int    pbase = chunk * PIX_PER_BLOCK;
    const int*   im    = indmap + (size_t)b * HW_ + pbase;
    const int*   vm    = valid  + (size_t)b * HW_ + pbase;
    const float* inp   = input  + ((size_t)b * C_ + (size_t)g * CG) * HW_ + pbase;

    // 4 consecutive pixels/thread/iter; branch-free; native ds_add_u32 atomics.
    for (int it = 0; it < PIX_PER_BLOCK / (THREADS * 4); ++it) {   // 4 iters
        const int   p0  = it * (THREADS * 4) + t * 4;
        const i32x4 idx = *reinterpret_cast<const i32x4*>(im + p0);
        const i32x4 v   = *reinterpret_cast<const i32x4*>(vm + p0);
        // mask folded into the fixed-point scale (decoded ONCE for all 8 channels)
        const float mx = v.x ? SCALE_F : 0.0f;
        const float my = v.y ? SCALE_F : 0.0f;
        const float mz = v.z ? SCALE_F : 0.0f;
        const float mw = v.w ? SCALE_F : 0.0f;

        // ---- batch A: channels 0..3 ----
        {
            const f32x4 x0 = *reinterpret_cast<const f32x4*>(inp + 0 * (size_t)HW_ + p0);
            const f32x4 x1 = *reinterpret_cast<const f32x4*>(inp + 1 * (size_t)HW_ + p0);
            const f32x4 x2 = *reinterpret_cast<const f32x4*>(inp + 2 * (size_t)HW_ + p0);
            const f32x4 x3 = *reinterpret_cast<const f32x4*>(inp + 3 * (size_t)HW_ + p0);

            unsigned* a0 = &acc[0 * L_];
            unsigned* a1 = &acc[1 * L_];
            unsigned* a2 = &acc[2 * L_];
            unsigned* a3 = &acc[3 * L_];

            atomicAdd(&a0[idx.x], (unsigned)__float2int_rn(x0.x * mx));
            atomicAdd(&a0[idx.y], (unsigned)__float2int_rn(x0.y * my));
            atomicAdd(&a0[idx.z], (unsigned)__float2int_rn(x0.z * mz));
            atomicAdd(&a0[idx.w], (unsigned)__float2int_rn(x0.w * mw));

            atomicAdd(&a1[idx.x], (unsigned)__float2int_rn(x1.x * mx));
            atomicAdd(&a1[idx.y], (unsigned)__float2int_rn(x1.y * my));
            atomicAdd(&a1[idx.z], (unsigned)__float2int_rn(x1.z * mz));
            atomicAdd(&a1[idx.w], (unsigned)__float2int_rn(x1.w * mw));

            atomicAdd(&a2[idx.x], (unsigned)__float2int_rn(x2.x * mx));
            atomicAdd(&a2[idx.y], (unsigned)__float2int_rn(x2.y * my));
            atomicAdd(&a2[idx.z], (unsigned)__float2int_rn(x2.z * mz));
            atomicAdd(&a2[idx.w], (unsigned)__float2int_rn(x2.w * mw));

            atomicAdd(&a3[idx.x], (unsigned)__float2int_rn(x3.x * mx));
            atomicAdd(&a3[idx.y], (unsigned)__float2int_rn(x3.y * my));
            atomicAdd(&a3[idx.z], (unsigned)__float2int_rn(x3.z * mz));
            atomicAdd(&a3[idx.w], (unsigned)__float2int_rn(x3.w * mw));
        }

        // ---- batch B: channels 4..7 (reuses idx/mask registers) ----
        {
            const f32x4 x4 = *reinterpret_cast<const f32x4*>(inp + 4 * (size_t)HW_ + p0);
            const f32x4 x5 = *reinterpret_cast<const f32x4*>(inp + 5 * (size_t)HW_ + p0);
            const f32x4 x6 = *reinterpret_cast<const f32x4*>(inp + 6 * (size_t)HW_ + p0);
            const f32x4 x7 = *reinterpret_cast<const f32x4*>(inp + 7 * (size_t)HW_ + p0);

            unsigned* a4 = &acc[4 * L_];
            unsigned* a5 = &acc[5 * L_];
            unsigned* a6 = &acc[6 * L_];
            unsigned* a7 = &acc[7 * L_];

            atomicAdd(&a4[idx.x], (unsigned)__float2int_rn(x4.x * mx));
            atomicAdd(&a4[idx.y], (unsigned)__float2int_rn(x4.y * my));
            atomicAdd(&a4[idx.z], (unsigned)__float2int_rn(x4.z * mz));
            atomicAdd(&a4[idx.w], (unsigned)__float2int_rn(x4.w * mw));

            atomicAdd(&a5[idx.x], (unsigned)__float2int_rn(x5.x * mx));
            atomicAdd(&a5[idx.y], (unsigned)__float2int_rn(x5.y * my));
            atomicAdd(&a5[idx.z], (unsigned)__float2int_rn(x5.z * mz));
            atomicAdd(&a5[idx.w], (unsigned)__float2int_rn(x5.w * mw));

            atomicAdd(&a6[idx.x], (unsigned)__float2int_rn(x6.x * mx));
            atomicAdd(&a6[idx.y], (unsigned)__float2int_rn(x6.y * my));
            atomicAdd(&a6[idx.z], (unsigned)__float2int_rn(x6.z * mz));
            atomicAdd(&a6[idx.w], (unsigned)__float2int_rn(x6.w * mw));

            atomicAdd(&a7[idx.x], (unsigned)__float2int_rn(x7.x * mx));
            atomicAdd(&a7[idx.y], (unsigned)__float2int_rn(x7.y * my));
            atomicAdd(&a7[idx.z], (unsigned)__float2int_rn(x7.z * mz));
            atomicAdd(&a7[idx.w], (unsigned)__float2int_rn(x7.w * mw));
        }
    }
    __syncthreads();

    // Flush: out[b,c,l] += acc * 2^-20 / cnt[b,l] via native fp32 atomic
    // (global_atomic_add_f32, no-return). Division distributes over the sum.
    const int* cnt = out_count + (size_t)b * L_;
    float*     ob  = out + ((size_t)b * C_ + (size_t)g * CG) * L_;
    for (int e = t; e < CG * L_; e += THREADS) {         // 16 per thread
        const int l = e & (L_ - 1);
        unsafeAtomicAdd(&ob[e], (float)(int)acc[e] * INV_SCALE_F / (float)cnt[l]);
    }
}

extern "C" void kernel_launch(void* const* d_in, const int* in_sizes, int n_in,
                              void* d_out, int out_size, void* d_ws, size_t ws_size,
                              hipStream_t stream) {
    const float* input     = (const float*)d_in[0];   // [B,C,H,W] fp32
    const int*   indmap    = (const int*)  d_in[1];   // [B,H,W]
    const int*   out_count = (const int*)  d_in[2];   // [B,L]
    const int*   valid     = (const int*)  d_in[3];   // [B,H,W]
    float*       out       = (float*)      d_out;     // [B,C,L]

    // Harness poisons d_out with 0xAA and never re-zeroes between replays.
    (void)hipMemsetAsync(out, 0, (size_t)out_size * sizeof(float), stream);

    const dim3 grid(B_ * GROUPS * BLOCKS_PER_B);                     // 2048 blocks
    pool_accum<<<grid, THREADS, 0, stream>>>(input, indmap, out_count, valid, out);
}

// Round 9
// 55.365 us; speedup vs baseline: 1.3533x; 1.3533x over previous
//
#include <hip/hip_runtime.h>

// Problem constants (match the reference's module-level B, C, H, W, L)
#define B_  8
#define C_  32
#define HW_ (512 * 512)
#define L_  512

#define CG            4                      // channels per block.
                                             // CG=8 measured WORSE twice (r5: 66.9us
                                             // monolithic, r8: 74.9us split-batch):
                                             // 8 input streams/block + 16KiB LDS +
                                             // 8-deep same-bank atomic chains/pixel.
#define GROUPS        (C_ / CG)              // 8
#define PIX_PER_BLOCK 8192
#define THREADS       256
#define BLOCKS_PER_B  (HW_ / PIX_PER_BLOCK)  // 32

// Fixed-point scale: input ~N(0,1), bin sums |.| <~ 150 -> 150*2^20 = 1.6e8 << 2^31.
// Quantization: <=0.5 ulp = 2^-21 per term, <=1024 terms/bin -> <=5e-4 abs error.
#define SCALE_F     1048576.0f               // 2^20
#define INV_SCALE_F (1.0f / 1048576.0f)

typedef float f32x4 __attribute__((ext_vector_type(4)));
typedef int   i32x4 __attribute__((ext_vector_type(4)));

// Measured-best structure (round 3, 55.5us e2e):
//   LDS int histogram + native ds_add_u32 (no-return) — fp atomicAdd on LDS
//   lowers to a CAS loop (~220cy/op, the round-1/2 poison; 6.3x slower).
//   8 KiB LDS, 24 VGPR -> thread-limited 8 blocks/CU, 32 waves/CU.
//   Plain loads: nontemporal hint measured -5.7% (r6) — L3 reuse matters.
__global__ __launch_bounds__(THREADS, 8)
void pool_accum(const float* __restrict__ input,      // [B,C,H,W]
                const int*   __restrict__ indmap,     // [B,H,W]
                const int*   __restrict__ valid,      // [B,H,W]
                unsigned*    __restrict__ wsAcc)      // [B,C,L] fixed-point
{
    __shared__ unsigned acc[CG * L_];   // 8 KiB

    const int bid   = blockIdx.x;
    const int b     = bid / (GROUPS * BLOCKS_PER_B);
    const int rem   = bid % (GROUPS * BLOCKS_PER_B);
    const int g     = rem / BLOCKS_PER_B;     // channel group
    const int chunk = rem % BLOCKS_PER_B;     // pixel chunk
    const int t     = threadIdx.x;

    for (int i = t; i < CG * L_; i += THREADS) acc[i] = 0u;
    __syncthreads();

    const int    pbase = chunk * PIX_PER_BLOCK;
    const int*   im    = indmap + (size_t)b * HW_ + pbase;
    const int*   vm    = valid  + (size_t)b * HW_ + pbase;
    const float* inp   = input  + ((size_t)b * C_ + (size_t)g * CG) * HW_ + pbase;

    // 4 consecutive pixels/thread/iter; branch-free; native ds_add_u32 atomics.
    for (int it = 0; it < PIX_PER_BLOCK / (THREADS * 4); ++it) {   // 8 iters
        const int   p0  = it * (THREADS * 4) + t * 4;
        const i32x4 idx = *reinterpret_cast<const i32x4*>(im + p0);
        const i32x4 v   = *reinterpret_cast<const i32x4*>(vm + p0);
        // mask folded into the fixed-point scale
        const float mx = v.x ? SCALE_F : 0.0f;
        const float my = v.y ? SCALE_F : 0.0f;
        const float mz = v.z ? SCALE_F : 0.0f;
        const float mw = v.w ? SCALE_F : 0.0f;

        const f32x4 x0 = *reinterpret_cast<const f32x4*>(inp + 0 * (size_t)HW_ + p0);
        const f32x4 x1 = *reinterpret_cast<const f32x4*>(inp + 1 * (size_t)HW_ + p0);
        const f32x4 x2 = *reinterpret_cast<const f32x4*>(inp + 2 * (size_t)HW_ + p0);
        const f32x4 x3 = *reinterpret_cast<const f32x4*>(inp + 3 * (size_t)HW_ + p0);

        unsigned* a0 = &acc[0 * L_];
        unsigned* a1 = &acc[1 * L_];
        unsigned* a2 = &acc[2 * L_];
        unsigned* a3 = &acc[3 * L_];

        atomicAdd(&a0[idx.x], (unsigned)__float2int_rn(x0.x * mx));
        atomicAdd(&a0[idx.y], (unsigned)__float2int_rn(x0.y * my));
        atomicAdd(&a0[idx.z], (unsigned)__float2int_rn(x0.z * mz));
        atomicAdd(&a0[idx.w], (unsigned)__float2int_rn(x0.w * mw));

        atomicAdd(&a1[idx.x], (unsigned)__float2int_rn(x1.x * mx));
        atomicAdd(&a1[idx.y], (unsigned)__float2int_rn(x1.y * my));
        atomicAdd(&a1[idx.z], (unsigned)__float2int_rn(x1.z * mz));
        atomicAdd(&a1[idx.w], (unsigned)__float2int_rn(x1.w * mw));

        atomicAdd(&a2[idx.x], (unsigned)__float2int_rn(x2.x * mx));
        atomicAdd(&a2[idx.y], (unsigned)__float2int_rn(x2.y * my));
        atomicAdd(&a2[idx.z], (unsigned)__float2int_rn(x2.z * mz));
        atomicAdd(&a2[idx.w], (unsigned)__float2int_rn(x2.w * mw));

        atomicAdd(&a3[idx.x], (unsigned)__float2int_rn(x3.x * mx));
        atomicAdd(&a3[idx.y], (unsigned)__float2int_rn(x3.y * my));
        atomicAdd(&a3[idx.z], (unsigned)__float2int_rn(x3.z * mz));
        atomicAdd(&a3[idx.w], (unsigned)__float2int_rn(x3.w * mw));
    }
    __syncthreads();

    // Flush partials: native no-return global u32 atomics into ws.
    unsigned* wb = wsAcc + ((size_t)b * C_ + (size_t)g * CG) * L_;
    for (int e = t; e < CG * L_; e += THREADS)           // 8 per thread
        atomicAdd(&wb[e], acc[e]);
}

// ws int [B,C,L] -> out float [B,C,L], divided by per-(b,l) count.
__global__ __launch_bounds__(256)
void pool_finalize(const int* __restrict__ wsAcc,
                   const int* __restrict__ out_count,
                   float*     __restrict__ out)
{
    const int e = blockIdx.x * 256 + threadIdx.x;   // < B*C*L
    const int b = e / (C_ * L_);
    const int l = e & (L_ - 1);
    out[e] = (float)wsAcc[e] * INV_SCALE_F / (float)out_count[b * L_ + l];
}

extern "C" void kernel_launch(void* const* d_in, const int* in_sizes, int n_in,
                              void* d_out, int out_size, void* d_ws, size_t ws_size,
                              hipStream_t stream) {
    const float* input     = (const float*)d_in[0];   // [B,C,H,W] fp32
    const int*   indmap    = (const int*)  d_in[1];   // [B,H,W]
    const int*   out_count = (const int*)  d_in[2];   // [B,L]
    const int*   valid     = (const int*)  d_in[3];   // [B,H,W]
    float*       out       = (float*)      d_out;     // [B,C,L]

    unsigned* wsAcc = (unsigned*)d_ws;                               // 512 KiB used
    (void)hipMemsetAsync(wsAcc, 0, (size_t)B_ * C_ * L_ * sizeof(int), stream);

    const dim3 grid(B_ * GROUPS * BLOCKS_PER_B);                     // 2048 blocks
    pool_accum<<<grid, THREADS, 0, stream>>>(input, indmap, valid, wsAcc);
    pool_finalize<<<(B_ * C_ * L_) / 256, 256, 0, stream>>>((const int*)wsAcc,
                                                            out_count, out);
}